// Round 2
// baseline (703.091 us; speedup 1.0000x reference)
//
#include <hip/hip_runtime.h>
#include <hip/hip_cooperative_groups.h>
#include <math.h>

namespace cg = cooperative_groups;

// EdgeConvGNN: 2-layer GCN on a line graph; output = sigmoid(h2[idx0].Wl+bl).
// Only the 2-hop neighborhood of idx0 is live, plus degrees of those ~120
// nodes. Single cooperative kernel, 7 phases / 6 grid syncs:
//   P0 scan col[]            -> list1 = edges with col==idx0
//   P1 (block0) dedup        -> S2 = {idx0} U rows(list1)   (bit flags)
//   P2 scan col[]            -> list2 = edges with col in S2
//   P3 (block0) dedup        -> S3 = rows(list2) U S2
//   P4 scan col[] (blocks 0..B-65): degc[slot[c]]++ for c in S3   (~1.2K atomics)
//      || (last 64 blocks)  hw0[s] = concat(x[src],x[dst]) @ W0 per S3 node
//   P5 one block per S2 node: h1 = relu(agg(list2)+self+b0); hw1 = h1 @ W1
//   P6 (block0) h2 = relu(agg(list1)+self+b1); out = sigmoid(h2.Wl+bl)
// No per-edge histogram atomics (was 62 MB of write traffic).

#define MAX_L1 1024
#define MAX_S2 1024
#define MAX_L2 8192
#define MAX_S3 8192
#define GRID_B 512
#define HW0_BLOCKS 64

enum { CNT_L1 = 0, CNT_S2 = 1, CNT_L2 = 2, CNT_S3 = 3 };

__global__ void __launch_bounds__(256, 2)
fused_gnn(const float* __restrict__ x, const int* __restrict__ g,
          const int* __restrict__ lg, const int* __restrict__ pidx,
          const float* __restrict__ W0, const float* __restrict__ b0,
          const float* __restrict__ W1, const float* __restrict__ b1,
          const float* __restrict__ Wl, const float* __restrict__ bl,
          float* __restrict__ out,
          int* __restrict__ cnt, unsigned* __restrict__ bits2,
          unsigned* __restrict__ bits3, int* __restrict__ degc,
          int* __restrict__ list1, int* __restrict__ s2_list,
          int* __restrict__ s2pos, int2* __restrict__ list2,
          int* __restrict__ s3_list, int* __restrict__ slot,
          float* __restrict__ hw0, float* __restrict__ hw1,
          int e_g, int e_lg) {
  cg::grid_group grid = cg::this_grid();
  const int tid = threadIdx.x;
  const int gtid = blockIdx.x * blockDim.x + tid;
  const int gstride = gridDim.x * blockDim.x;
  const int idx0 = pidx[0];
  const int* __restrict__ col = lg + e_lg;
  __shared__ float sh[128];

  // ---- P0: collect edges with col == idx0 ----
  for (int e = gtid; e < e_lg; e += gstride) {
    if (col[e] == idx0) {
      int p = atomicAdd(&cnt[CNT_L1], 1);
      if (p < MAX_L1) list1[p] = lg[e];
    }
  }
  __threadfence();
  grid.sync();

  // ---- P1: build S2 (block 0) ----
  if (blockIdx.x == 0) {
    int n1 = min(cnt[CNT_L1], MAX_L1);
    for (int i = tid; i < n1 + 1; i += blockDim.x) {
      int n = (i == 0) ? idx0 : list1[i - 1];
      unsigned m = 1u << (n & 31);
      unsigned old = atomicOr(&bits2[n >> 5], m);
      if (!(old & m)) {
        int p = atomicAdd(&cnt[CNT_S2], 1);
        s2_list[p] = n;
        s2pos[n] = p;
      }
    }
  }
  __threadfence();
  grid.sync();

  // ---- P2: collect edges with col in S2 ----
  for (int e = gtid; e < e_lg; e += gstride) {
    int c = col[e];
    if ((bits2[c >> 5] >> (c & 31)) & 1u) {
      int p = atomicAdd(&cnt[CNT_L2], 1);
      if (p < MAX_L2) list2[p] = make_int2(lg[e], c);
    }
  }
  __threadfence();
  grid.sync();

  // ---- P3: build S3 (block 0) ----
  if (blockIdx.x == 0) {
    int n2 = min(cnt[CNT_L2], MAX_L2);
    int ns2 = min(cnt[CNT_S2], MAX_S2);
    for (int i = tid; i < n2 + ns2; i += blockDim.x) {
      int n = (i < n2) ? list2[i].x : s2_list[i - n2];
      unsigned m = 1u << (n & 31);
      unsigned old = atomicOr(&bits3[n >> 5], m);
      if (!(old & m)) {
        int p = atomicAdd(&cnt[CNT_S3], 1);
        s3_list[p] = n;
        slot[n] = p;
      }
    }
  }
  __threadfence();
  grid.sync();

  // ---- P4: deg-count for S3 (first blocks)  ||  hw0 matvec (last 64 blocks) ----
  {
    int ns3 = min(cnt[CNT_S3], MAX_S3);
    if (blockIdx.x >= gridDim.x - HW0_BLOCKS) {
      // half-block (128 threads) per S3 node: hw0 = concat(x[src],x[dst]) @ W0
      int hb = (blockIdx.x - (gridDim.x - HW0_BLOCKS)) * 2 + (tid >> 7);
      int t = tid & 127;
      for (int b = hb; b < ns3; b += HW0_BLOCKS * 2) {
        int node = s3_list[b];
        int src = g[node];
        int dst = g[e_g + node];
        float acc = 0.f;
#pragma unroll 8
        for (int k = 0; k < 64; ++k) acc += x[src * 64 + k] * W0[k * 128 + t];
#pragma unroll 8
        for (int k = 0; k < 64; ++k) acc += x[dst * 64 + k] * W0[(64 + k) * 128 + t];
        hw0[b * 128 + t] = acc;
      }
    } else {
      int nscan = (gridDim.x - HW0_BLOCKS) * blockDim.x;
      for (int e = blockIdx.x * blockDim.x + tid; e < e_lg; e += nscan) {
        int c = col[e];
        if ((bits3[c >> 5] >> (c & 31)) & 1u) atomicAdd(&degc[slot[c]], 1);
      }
    }
  }
  __threadfence();
  grid.sync();

  // ---- P5: h1 = relu(aggregate + self + b0); hw1 = h1 @ W1 (block per S2 node) ----
  {
    int ns2 = min(cnt[CNT_S2], MAX_S2);
    int n2 = min(cnt[CNT_L2], MAX_L2);
    if (blockIdx.x < ns2) {
      int j = s2_list[blockIdx.x];
      int t = tid;
      if (t < 128) {
        float dj = rsqrtf((float)degc[slot[j]] + 1.0f);
        float acc = hw0[slot[j] * 128 + t] * dj * dj;  // self-loop
        for (int i = 0; i < n2; ++i) {
          int2 e = list2[i];
          if (e.y == j) {
            float dr = rsqrtf((float)degc[slot[e.x]] + 1.0f);
            acc += hw0[slot[e.x] * 128 + t] * (dr * dj);
          }
        }
        sh[t] = fmaxf(acc + b0[t], 0.f);
      }
      __syncthreads();
      if (t < 128) {
        float acc = 0.f;
#pragma unroll 8
        for (int k = 0; k < 128; ++k) acc += sh[k] * W1[k * 128 + t];
        hw1[blockIdx.x * 128 + t] = acc;
      }
    }
  }
  __threadfence();
  grid.sync();

  // ---- P6: final aggregate at idx0 + logit (block 0) ----
  if (blockIdx.x == 0) {
    int t = tid;
    if (t < 128) {
      float d0 = rsqrtf((float)degc[slot[idx0]] + 1.0f);
      float acc = hw1[s2pos[idx0] * 128 + t] * d0 * d0;  // self-loop
      int n1 = min(cnt[CNT_L1], MAX_L1);
      for (int i = 0; i < n1; ++i) {
        int r = list1[i];
        float dr = rsqrtf((float)degc[slot[r]] + 1.0f);
        acc += hw1[s2pos[r] * 128 + t] * (dr * d0);
      }
      float h2 = fmaxf(acc + b1[t], 0.f);
      sh[t] = h2 * Wl[t];
    }
    __syncthreads();
    for (int s = 64; s > 0; s >>= 1) {
      if (t < s) sh[t] += sh[t + s];
      __syncthreads();
    }
    if (t == 0) out[0] = 1.f / (1.f + expf(-(sh[0] + bl[0])));
  }
}

extern "C" void kernel_launch(void* const* d_in, const int* in_sizes, int n_in,
                              void* d_out, int out_size, void* d_ws, size_t ws_size,
                              hipStream_t stream) {
  const float* x  = (const float*)d_in[0];
  const int* g    = (const int*)d_in[1];
  const int* lg   = (const int*)d_in[2];
  const int* pidx = (const int*)d_in[3];
  const float* W0 = (const float*)d_in[4];
  const float* b0 = (const float*)d_in[5];
  const float* W1 = (const float*)d_in[6];
  const float* b1 = (const float*)d_in[7];
  const float* Wl = (const float*)d_in[8];
  const float* bl = (const float*)d_in[9];
  float* out = (float*)d_out;

  int e_g = in_sizes[1] / 2;   // 200000
  int e_lg = in_sizes[2] / 2;  // 2000000

  // ---- workspace layout ----
  char* ws = (char*)d_ws;
  size_t off = 0;
  auto take = [&](size_t bytes) {
    size_t cur = off;
    off = (off + bytes + 15) & ~(size_t)15;
    return cur;
  };
  const size_t nbits_words = ((size_t)e_g + 31) / 32;
  int* cnt        = (int*)(ws + take(16 * 4));
  unsigned* bits2 = (unsigned*)(ws + take(nbits_words * 4));
  unsigned* bits3 = (unsigned*)(ws + take(nbits_words * 4));
  int* degc       = (int*)(ws + take((size_t)MAX_S3 * 4));
  size_t zero_bytes = off;  // ~83 KB: cnt + bit-flags + degc
  int* list1      = (int*)(ws + take(MAX_L1 * 4));
  int* s2_list    = (int*)(ws + take(MAX_S2 * 4));
  int* s2pos      = (int*)(ws + take((size_t)e_g * 4));
  int2* list2     = (int2*)(ws + take((size_t)MAX_L2 * 8));
  int* s3_list    = (int*)(ws + take(MAX_S3 * 4));
  int* slot       = (int*)(ws + take((size_t)e_g * 4));
  float* hw0      = (float*)(ws + take((size_t)MAX_S3 * 128 * 4));
  float* hw1      = (float*)(ws + take((size_t)MAX_S2 * 128 * 4));
  (void)ws_size;

  hipMemsetAsync(d_ws, 0, zero_bytes, stream);

  void* kargs[] = {
      (void*)&x,   (void*)&g,       (void*)&lg,      (void*)&pidx,
      (void*)&W0,  (void*)&b0,      (void*)&W1,      (void*)&b1,
      (void*)&Wl,  (void*)&bl,      (void*)&out,
      (void*)&cnt, (void*)&bits2,   (void*)&bits3,   (void*)&degc,
      (void*)&list1, (void*)&s2_list, (void*)&s2pos, (void*)&list2,
      (void*)&s3_list, (void*)&slot, (void*)&hw0,    (void*)&hw1,
      (void*)&e_g, (void*)&e_lg};
  hipLaunchCooperativeKernel((const void*)fused_gnn, dim3(GRID_B), dim3(256),
                             kargs, 0, stream);
}

// Round 3
// 148.197 us; speedup vs baseline: 4.7443x; 4.7443x over previous
//
#include <hip/hip_runtime.h>
#include <math.h>

// EdgeConvGNN: 2-layer GCN on a line graph; output = sigmoid(h2[idx0].Wl+bl).
// Only the 2-hop neighborhood of idx0 is live. Stream-ordered kernels (no
// grid.sync — measured ~100us/phase on 8-XCD MI355X), no full-degree
// histogram (was 62 MB of atomic write traffic):
//   K1 scan col[] -> list1 (edges with col==idx0), build S2 (+seed S3) inline
//   K2 scan col[] -> list2 (edges with col in S2), build S3 inline
//   K3 scan col[] -> degc[slot[c]]++ for c in S3 (~1.2K atomics)
//      || last 64 blocks: hw0[b] = concat(x[src],x[dst]) @ W0 per S3 node
//   K4 per S2 node: h1 = relu(agg(list2)+self+b0); hw1 = h1 @ W1
//   K5 final aggregate at idx0 + sigmoid
#define MAX_L1 512
#define MAX_S2 (MAX_L1 + 8)
#define MAX_L2 4096
#define MAX_S3 (MAX_L2 + MAX_S2 + 8)
#define SCAN_BLOCKS 2048
#define HW0_BLOCKS 64

enum { CNT_L1 = 0, CNT_S2 = 1, CNT_L2 = 2, CNT_S3 = 3 };

__device__ __forceinline__ void insert_s3(int n, unsigned* bits3, int* cnt,
                                          int* s3_list, int* slot) {
  unsigned m = 1u << (n & 31);
  if (!(atomicOr(&bits3[n >> 5], m) & m)) {
    int p = atomicAdd(&cnt[CNT_S3], 1);
    if (p < MAX_S3) { s3_list[p] = n; slot[n] = p; }
  }
}

__device__ __forceinline__ void insert_s2(int n, unsigned* bits2, int* cnt,
                                          int* s2_list, int* s2pos,
                                          unsigned* bits3, int* s3_list,
                                          int* slot) {
  unsigned m = 1u << (n & 31);
  if (!(atomicOr(&bits2[n >> 5], m) & m)) {
    int p = atomicAdd(&cnt[CNT_S2], 1);
    if (p < MAX_S2) { s2_list[p] = n; s2pos[n] = p; }
  }
  insert_s3(n, bits3, cnt, s3_list, slot);
}

// K1: list1 = edges with col==idx0; S2 = {idx0} U rows(list1)
__global__ void __launch_bounds__(256) k_scan1(
    const int* __restrict__ lg, int e_lg, const int* __restrict__ pidx,
    int* __restrict__ cnt, unsigned* __restrict__ bits2,
    unsigned* __restrict__ bits3, int* __restrict__ list1,
    int* __restrict__ s2_list, int* __restrict__ s2pos,
    int* __restrict__ s3_list, int* __restrict__ slot) {
  const int idx0 = pidx[0];
  const int gtid = blockIdx.x * blockDim.x + threadIdx.x;
  const int gstride = gridDim.x * blockDim.x;
  if (gtid == 0) insert_s2(idx0, bits2, cnt, s2_list, s2pos, bits3, s3_list, slot);
  const int* __restrict__ col = lg + e_lg;
  const int n4 = ((((uintptr_t)col) & 15) == 0) ? (e_lg >> 2) : 0;
  const int4* __restrict__ col4 = (const int4*)col;
  for (int i = gtid; i < n4; i += gstride) {
    int4 v = col4[i];
    int cc[4] = {v.x, v.y, v.z, v.w};
#pragma unroll
    for (int k = 0; k < 4; ++k) {
      if (cc[k] == idx0) {
        int r = lg[i * 4 + k];
        int p = atomicAdd(&cnt[CNT_L1], 1);
        if (p < MAX_L1) list1[p] = r;
        insert_s2(r, bits2, cnt, s2_list, s2pos, bits3, s3_list, slot);
      }
    }
  }
  for (int e = n4 * 4 + gtid; e < e_lg; e += gstride) {
    if (col[e] == idx0) {
      int r = lg[e];
      int p = atomicAdd(&cnt[CNT_L1], 1);
      if (p < MAX_L1) list1[p] = r;
      insert_s2(r, bits2, cnt, s2_list, s2pos, bits3, s3_list, slot);
    }
  }
}

// K2: list2 = edges with col in S2; S3 += rows(list2)
__global__ void __launch_bounds__(256) k_scan2(
    const int* __restrict__ lg, int e_lg, int* __restrict__ cnt,
    const unsigned* __restrict__ bits2, unsigned* __restrict__ bits3,
    int2* __restrict__ list2, int* __restrict__ s3_list,
    int* __restrict__ slot) {
  const int gtid = blockIdx.x * blockDim.x + threadIdx.x;
  const int gstride = gridDim.x * blockDim.x;
  const int* __restrict__ col = lg + e_lg;
  const int n4 = ((((uintptr_t)col) & 15) == 0) ? (e_lg >> 2) : 0;
  const int4* __restrict__ col4 = (const int4*)col;
  for (int i = gtid; i < n4; i += gstride) {
    int4 v = col4[i];
    int cc[4] = {v.x, v.y, v.z, v.w};
#pragma unroll
    for (int k = 0; k < 4; ++k) {
      int c = cc[k];
      if ((bits2[c >> 5] >> (c & 31)) & 1u) {
        int r = lg[i * 4 + k];
        int p = atomicAdd(&cnt[CNT_L2], 1);
        if (p < MAX_L2) list2[p] = make_int2(r, c);
        insert_s3(r, bits3, cnt, s3_list, slot);
      }
    }
  }
  for (int e = n4 * 4 + gtid; e < e_lg; e += gstride) {
    int c = col[e];
    if ((bits2[c >> 5] >> (c & 31)) & 1u) {
      int r = lg[e];
      int p = atomicAdd(&cnt[CNT_L2], 1);
      if (p < MAX_L2) list2[p] = make_int2(r, c);
      insert_s3(r, bits3, cnt, s3_list, slot);
    }
  }
}

// K3: degree scan for S3 nodes || hw0 matvec (last HW0_BLOCKS blocks)
__global__ void __launch_bounds__(256) k_deg_hw0(
    const int* __restrict__ lg, int e_lg, const float* __restrict__ x,
    const int* __restrict__ g, int e_g, const float* __restrict__ W0,
    const int* __restrict__ cnt, const unsigned* __restrict__ bits3,
    const int* __restrict__ slot, int* __restrict__ degc,
    const int* __restrict__ s3_list, float* __restrict__ hw0) {
  const int tid = threadIdx.x;
  if (blockIdx.x < gridDim.x - HW0_BLOCKS) {
    const int gtid = blockIdx.x * blockDim.x + tid;
    const int gstride = (gridDim.x - HW0_BLOCKS) * blockDim.x;
    const int* __restrict__ col = lg + e_lg;
    const int n4 = ((((uintptr_t)col) & 15) == 0) ? (e_lg >> 2) : 0;
    const int4* __restrict__ col4 = (const int4*)col;
    for (int i = gtid; i < n4; i += gstride) {
      int4 v = col4[i];
      int cc[4] = {v.x, v.y, v.z, v.w};
#pragma unroll
      for (int k = 0; k < 4; ++k) {
        int c = cc[k];
        if ((bits3[c >> 5] >> (c & 31)) & 1u) atomicAdd(&degc[slot[c]], 1);
      }
    }
    for (int e = n4 * 4 + gtid; e < e_lg; e += gstride) {
      int c = col[e];
      if ((bits3[c >> 5] >> (c & 31)) & 1u) atomicAdd(&degc[slot[c]], 1);
    }
  } else {
    int ns3 = min(cnt[CNT_S3], MAX_S3);
    int hb = (blockIdx.x - (gridDim.x - HW0_BLOCKS)) * 2 + (tid >> 7);
    int t = tid & 127;
    for (int b = hb; b < ns3; b += HW0_BLOCKS * 2) {
      int node = s3_list[b];
      int src = g[node];
      int dst = g[e_g + node];
      float acc = 0.f;
#pragma unroll 8
      for (int k = 0; k < 64; ++k) acc += x[src * 64 + k] * W0[k * 128 + t];
#pragma unroll 8
      for (int k = 0; k < 64; ++k) acc += x[dst * 64 + k] * W0[(64 + k) * 128 + t];
      hw0[b * 128 + t] = acc;
    }
  }
}

// K4: per S2 node: h1 = relu(agg + self + b0); hw1 = h1 @ W1
__global__ void __launch_bounds__(256) k_h1_hw1(
    const int* __restrict__ cnt, const int* __restrict__ s2_list,
    const int* __restrict__ slot, const int* __restrict__ degc,
    const int2* __restrict__ list2, const float* __restrict__ hw0,
    const float* __restrict__ b0, const float* __restrict__ W1,
    float* __restrict__ hw1) {
  int ns2 = min(cnt[CNT_S2], MAX_S2);
  if ((int)blockIdx.x >= ns2) return;
  int j = s2_list[blockIdx.x];
  int t = threadIdx.x & 127;
  int grp = threadIdx.x >> 7;  // 0 or 1
  __shared__ float part[2][128];
  __shared__ float h1s[128];
  float dj = rsqrtf((float)degc[slot[j]] + 1.0f);
  float acc = (grp == 0) ? hw0[slot[j] * 128 + t] * dj * dj + b0[t] : 0.f;
  int n2 = min(cnt[CNT_L2], MAX_L2);
  for (int i = grp; i < n2; i += 2) {
    int2 e = list2[i];
    if (e.y == j) {
      float dr = rsqrtf((float)degc[slot[e.x]] + 1.0f);
      acc += hw0[slot[e.x] * 128 + t] * (dr * dj);
    }
  }
  part[grp][t] = acc;
  __syncthreads();
  if (grp == 0) h1s[t] = fmaxf(part[0][t] + part[1][t], 0.f);
  __syncthreads();
  // hw1 = h1 @ W1: each group handles half the k-range
  float a2 = 0.f;
  int k0 = grp * 64;
#pragma unroll 8
  for (int k = 0; k < 64; ++k) a2 += h1s[k0 + k] * W1[(k0 + k) * 128 + t];
  part[grp][t] = a2;
  __syncthreads();
  if (grp == 0) hw1[blockIdx.x * 128 + t] = part[0][t] + part[1][t];
}

// K5: final aggregate at idx0 + logit
__global__ void __launch_bounds__(128) k_final(
    const int* __restrict__ cnt, const int* __restrict__ pidx,
    const int* __restrict__ list1, const int* __restrict__ s2pos,
    const int* __restrict__ slot, const int* __restrict__ degc,
    const float* __restrict__ hw1, const float* __restrict__ b1,
    const float* __restrict__ Wl, const float* __restrict__ bl,
    float* __restrict__ out) {
  int t = threadIdx.x;
  int idx0 = pidx[0];
  float d0 = rsqrtf((float)degc[slot[idx0]] + 1.0f);
  float acc = hw1[s2pos[idx0] * 128 + t] * d0 * d0;  // self-loop
  int n1 = min(cnt[CNT_L1], MAX_L1);
  for (int i = 0; i < n1; ++i) {
    int r = list1[i];
    float dr = rsqrtf((float)degc[slot[r]] + 1.0f);
    acc += hw1[s2pos[r] * 128 + t] * (dr * d0);
  }
  float h2 = fmaxf(acc + b1[t], 0.f);
  __shared__ float red[128];
  red[t] = h2 * Wl[t];
  __syncthreads();
  for (int s = 64; s > 0; s >>= 1) {
    if (t < s) red[t] += red[t + s];
    __syncthreads();
  }
  if (t == 0) out[0] = 1.f / (1.f + expf(-(red[0] + bl[0])));
}

extern "C" void kernel_launch(void* const* d_in, const int* in_sizes, int n_in,
                              void* d_out, int out_size, void* d_ws, size_t ws_size,
                              hipStream_t stream) {
  const float* x  = (const float*)d_in[0];
  const int* g    = (const int*)d_in[1];
  const int* lg   = (const int*)d_in[2];
  const int* pidx = (const int*)d_in[3];
  const float* W0 = (const float*)d_in[4];
  const float* b0 = (const float*)d_in[5];
  const float* W1 = (const float*)d_in[6];
  const float* b1 = (const float*)d_in[7];
  const float* Wl = (const float*)d_in[8];
  const float* bl = (const float*)d_in[9];
  float* out = (float*)d_out;

  int e_g = in_sizes[1] / 2;   // 200000
  int e_lg = in_sizes[2] / 2;  // 2000000

  // ---- workspace layout ----
  char* ws = (char*)d_ws;
  size_t off = 0;
  auto take = [&](size_t bytes) {
    size_t cur = off;
    off = (off + bytes + 15) & ~(size_t)15;
    return cur;
  };
  const size_t nbits_words = ((size_t)e_g + 31) / 32;
  int* cnt        = (int*)(ws + take(16 * 4));
  unsigned* bits2 = (unsigned*)(ws + take(nbits_words * 4));
  unsigned* bits3 = (unsigned*)(ws + take(nbits_words * 4));
  int* degc       = (int*)(ws + take((size_t)MAX_S3 * 4));
  size_t zero_bytes = off;  // ~70 KB
  int* list1      = (int*)(ws + take(MAX_L1 * 4));
  int* s2_list    = (int*)(ws + take(MAX_S2 * 4));
  int* s2pos      = (int*)(ws + take((size_t)e_g * 4));
  int2* list2     = (int2*)(ws + take((size_t)MAX_L2 * 8));
  int* s3_list    = (int*)(ws + take((size_t)MAX_S3 * 4));
  int* slot       = (int*)(ws + take((size_t)e_g * 4));
  float* hw0      = (float*)(ws + take((size_t)MAX_S3 * 128 * 4));
  float* hw1      = (float*)(ws + take((size_t)MAX_S2 * 128 * 4));
  (void)ws_size;

  hipMemsetAsync(d_ws, 0, zero_bytes, stream);

  k_scan1<<<SCAN_BLOCKS, 256, 0, stream>>>(lg, e_lg, pidx, cnt, bits2, bits3,
                                           list1, s2_list, s2pos, s3_list, slot);
  k_scan2<<<SCAN_BLOCKS, 256, 0, stream>>>(lg, e_lg, cnt, bits2, bits3, list2,
                                           s3_list, slot);
  k_deg_hw0<<<SCAN_BLOCKS + HW0_BLOCKS, 256, 0, stream>>>(
      lg, e_lg, x, g, e_g, W0, cnt, bits3, slot, degc, s3_list, hw0);
  k_h1_hw1<<<MAX_S2, 256, 0, stream>>>(cnt, s2_list, slot, degc, list2, hw0, b0,
                                       W1, hw1);
  k_final<<<1, 128, 0, stream>>>(cnt, pidx, list1, s2pos, slot, degc, hw1, b1,
                                 Wl, bl, out);
}